// Round 2
// baseline (113.467 us; speedup 1.0000x reference)
//
#include <hip/hip_runtime.h>
#include <math.h>

#define NQ   12
#define NL   6
#define DIM  4096      // 2^12 amplitudes
#define BATCH 256
#define NT   512       // threads per block: 8 waves/CU = 2 waves/SIMD
#define PI2  9.869604401089358f   // pi*pi

__device__ __forceinline__ float geluf(float x) {
    return 0.5f * x * (1.0f + erff(x * 0.70710678118654752f));
}

// LDS slot padding (+1 float2 per 16): all four pass strides verified
// conflict-free (or free 2-way) per 16-lane phase.
__device__ __forceinline__ int slotf(int j) { return j + (j >> 4); }

__device__ __forceinline__ float2 cmul(float2 a, float2 b) {
    return make_float2(fmaf(a.x, b.x, -a.y * b.y), fmaf(a.x, b.y, a.y * b.x));
}
__device__ __forceinline__ float2 cadd(float2 a, float2 b) {
    return make_float2(a.x + b.x, a.y + b.y);
}
__device__ __forceinline__ float2 cscale(float2 a, float s) {
    return make_float2(a.x * s, a.y * s);
}

__global__ __launch_bounds__(NT)
void qpu_kernel(const float* __restrict__ x,   const float* __restrict__ W1, const float* __restrict__ b1,
                const float* __restrict__ g_ln, const float* __restrict__ b_ln,
                const float* __restrict__ W2,  const float* __restrict__ b2,
                const float* __restrict__ W3,  const float* __restrict__ b3,
                const float* __restrict__ qw,  const float* __restrict__ W4, const float* __restrict__ b4,
                const float* __restrict__ W5,  const float* __restrict__ b5,
                float* __restrict__ out)
{
    // ping-pong state buffers: permuted (CNOT-fused) reads need no mid-pass barrier
    __shared__ float2 st[2][DIM + DIM / 16];   // 2 x 34,816 B
    __shared__ float2 Um[NL * NQ * 4];         // 72 gates x 2x2 complex
    __shared__ float  xs[256];
    __shared__ float  h1n[128];
    __shared__ float  h2s[64];
    __shared__ float  xqs[NQ];
    __shared__ float  musd[2];
    __shared__ float  qv[3];
    __shared__ float  h4s[32];
    __shared__ float  zred[8][3];

    const int t = threadIdx.x;
    const int b = blockIdx.x;

    // ----------------- front-end MLP -----------------
    if (t < 256) xs[t] = x[b * 256 + t];
    __syncthreads();

    // h1 = gelu(x @ W1.T + b1) : 128 outputs, dot-256
    if (t < 128) {
        const float4* w = (const float4*)(W1 + t * 256);
        float a0 = 0.f, a1 = 0.f, a2 = 0.f, a3 = 0.f;
        #pragma unroll 8
        for (int k = 0; k < 64; k++) {
            float4 wv = w[k];
            const float* xp = &xs[4 * k];
            a0 = fmaf(wv.x, xp[0], a0);
            a1 = fmaf(wv.y, xp[1], a1);
            a2 = fmaf(wv.z, xp[2], a2);
            a3 = fmaf(wv.w, xp[3], a3);
        }
        h1n[t] = geluf((a0 + a1) + (a2 + a3) + b1[t]);
    }
    __syncthreads();

    // layernorm stats (wave 0 reduces 128 values)
    if (t < 64) {
        float v0 = h1n[t], v1 = h1n[t + 64];
        float s1 = v0 + v1;
        float s2 = fmaf(v0, v0, v1 * v1);
        #pragma unroll
        for (int off = 32; off > 0; off >>= 1) {
            s1 += __shfl_down(s1, off);
            s2 += __shfl_down(s2, off);
        }
        if (t == 0) {
            float mu  = s1 * (1.f / 128.f);
            float var = s2 * (1.f / 128.f) - mu * mu;
            musd[0] = mu;
            musd[1] = rsqrtf(var + 1e-5f);
        }
    }
    __syncthreads();
    if (t < 128) {
        h1n[t] = (h1n[t] - musd[0]) * musd[1] * g_ln[t] + b_ln[t];
    }
    __syncthreads();

    // h2 = gelu(h1n @ W2.T + b2) : 64 outputs, dot-128
    if (t < 64) {
        const float4* w = (const float4*)(W2 + t * 128);
        float a0 = 0.f, a1 = 0.f, a2 = 0.f, a3 = 0.f;
        #pragma unroll 8
        for (int k = 0; k < 32; k++) {
            float4 wv = w[k];
            const float* hp = &h1n[4 * k];
            a0 = fmaf(wv.x, hp[0], a0);
            a1 = fmaf(wv.y, hp[1], a1);
            a2 = fmaf(wv.z, hp[2], a2);
            a3 = fmaf(wv.w, hp[3], a3);
        }
        h2s[t] = geluf((a0 + a1) + (a2 + a3) + b2[t]);
    }
    __syncthreads();

    // xq = tanh(h2 @ W3.T + b3)
    if (t < NQ) {
        const float4* w = (const float4*)(W3 + t * 64);
        float a0 = 0.f, a1 = 0.f, a2 = 0.f, a3 = 0.f;
        #pragma unroll
        for (int k = 0; k < 16; k++) {
            float4 wv = w[k];
            const float* hp = &h2s[4 * k];
            a0 = fmaf(wv.x, hp[0], a0);
            a1 = fmaf(wv.y, hp[1], a1);
            a2 = fmaf(wv.z, hp[2], a2);
            a3 = fmaf(wv.w, hp[3], a3);
        }
        xqs[t] = tanhf((a0 + a1) + (a2 + a3) + b3[t]);
    }
    __syncthreads();

    // ----------------- gate matrices -----------------
    // U(l,i) = RZ(w2) RY(w1) RZ(w0), premultiplied by the preceding encoding
    // RY (initial enc for l=0; 0.5*enc for l=1,3,5 — encoding follows layers 0,2,4).
    if (t < NL * NQ) {
        const int l = t / NQ;
        const int i = t % NQ;
        float a  = qw[t * 3 + 0];
        float bb = qw[t * 3 + 1];
        float c  = qw[t * 3 + 2];
        float sb, cb;   sincosf(0.5f * bb, &sb, &cb);
        float apc = 0.5f * (a + c), amc = 0.5f * (a - c);
        float sapc, capc; sincosf(apc, &sapc, &capc);
        float samc, camc; sincosf(amc, &samc, &camc);
        float2 u00 = make_float2( cb * capc, -cb * sapc);
        float2 u01 = make_float2(-sb * camc, -sb * samc);
        float2 u10 = make_float2( sb * camc, -sb * samc);
        float2 u11 = make_float2( cb * capc,  cb * sapc);

        float theta = 0.f;
        bool merge = false;
        if (l == 0)      { theta = xqs[i] * PI2;        merge = true; }
        else if (l & 1)  { theta = xqs[i] * PI2 * 0.5f; merge = true; }
        if (merge) {
            float sy, cy; sincosf(0.5f * theta, &sy, &cy);
            float2 m00 = cadd(cscale(u00,  cy), cscale(u01, sy));
            float2 m01 = cadd(cscale(u00, -sy), cscale(u01, cy));
            float2 m10 = cadd(cscale(u10,  cy), cscale(u11, sy));
            float2 m11 = cadd(cscale(u10, -sy), cscale(u11, cy));
            u00 = m00; u01 = m01; u10 = m10; u11 = m11;
        }
        Um[t * 4 + 0] = u00;
        Um[t * 4 + 1] = u01;
        Um[t * 4 + 2] = u10;
        Um[t * 4 + 3] = u11;
    }
    __syncthreads();

    // ----------------- circuit -----------------
    // Per layer: 4 passes of 3 qubits (8-amp register subspaces).
    // Pass 0 reads the PREVIOUS layer's buffer through the fused CNOT
    // permutation (+CZ sign for l=2,4); layer 5's CNOT/CZ are folded into
    // the measurement parities. Layer 0 pass 0 starts from |0...0> directly.
    float2 a[8];
    float z0 = 0.f, z1 = 0.f, z2 = 0.f;

    for (int l = 0; l < NL; l++) {
        const float2* UL  = &Um[l * NQ * 4];
        float2*       dst = st[l & 1];
        const float2* srcb = st[(l & 1) ^ 1];

        #pragma unroll
        for (int c = 0; c < 4; c++) {
            const int P    = 9 - 3 * c;
            const int low  = t & ((1 << P) - 1);
            const int base = ((t >> P) << (P + 3)) | low;

            // ---- load 8-amp subspace ----
            if (c == 0) {
                if (l == 0) {
                    #pragma unroll
                    for (int m = 0; m < 8; m++) a[m] = make_float2(0.f, 0.f);
                    if (t == 0) a[0] = make_float2(1.f, 0.f);
                } else {
                    const bool czl = (l == 2) || (l == 4);
                    #pragma unroll
                    for (int m = 0; m < 8; m++) {
                        const int j = base | (m << 9);
                        const int src = ((j ^ (j >> 1)) & 0x3FF)
                                      | ((((j >> 10) ^ (j >> 11) ^ j) & 1) << 10)
                                      | ((((j >> 11) ^ j) & 1) << 11);
                        float2 v = srcb[slotf(src)];
                        if (czl) {
                            if (__popc(j & (j << 2) & 0xAA8) & 1) { v.x = -v.x; v.y = -v.y; }
                        }
                        a[m] = v;
                    }
                }
            } else {
                #pragma unroll
                for (int m = 0; m < 8; m++) a[m] = dst[slotf(base | (m << P))];
            }

            // ---- apply 3 gates: qubit 3c+k at local bit (4>>k) ----
            float2 uu[12];
            #pragma unroll
            for (int e = 0; e < 12; e++) uu[e] = UL[(3 * c) * 4 + e];
            #pragma unroll
            for (int k = 0; k < 3; k++) {
                const float2 u0 = uu[k * 4 + 0];
                const float2 u1 = uu[k * 4 + 1];
                const float2 u2 = uu[k * 4 + 2];
                const float2 u3 = uu[k * 4 + 3];
                const int bit = 4 >> k;
                #pragma unroll
                for (int m = 0; m < 8; m++) {
                    if (m & bit) continue;
                    float2 x0 = a[m], x1 = a[m | bit];
                    a[m]       = cadd(cmul(u0, x0), cmul(u1, x1));
                    a[m | bit] = cadd(cmul(u2, x0), cmul(u3, x1));
                }
            }

            // ---- store (skip on the very last pass: measured from regs) ----
            if (!(l == NL - 1 && c == 3)) {
                #pragma unroll
                for (int m = 0; m < 8; m++) dst[slotf(base | (m << P))] = a[m];
                __syncthreads();
            }
        }
    }

    // ----------------- measurement -----------------
    // Final state f[F(i)] = (CZ phase) * s[i]; |.|^2 kills the phase, and
    // F's bits 11/10/9 are parities of i with masks 0x7FF / 0xC00 / 0xE00.
    // Here i = 8t + m  (last pass P=0).
    {
        float sp = 0.f, so = 0.f;
        #pragma unroll
        for (int m = 0; m < 8; m++) {
            float p = fmaf(a[m].x, a[m].x, a[m].y * a[m].y);
            if (__popc(m) & 1) so += p; else sp += p;
        }
        const float stot = sp + so;
        z0 = (__popc(t & 0xFF)  & 1) ? (so - sp) : (sp - so);
        z1 = (__popc(t & 0x180) & 1) ? -stot : stot;
        z2 = (__popc(t & 0x1C0) & 1) ? -stot : stot;
    }
    #pragma unroll
    for (int off = 32; off > 0; off >>= 1) {
        z0 += __shfl_down(z0, off);
        z1 += __shfl_down(z1, off);
        z2 += __shfl_down(z2, off);
    }
    if ((t & 63) == 0) {
        zred[t >> 6][0] = z0;
        zred[t >> 6][1] = z1;
        zred[t >> 6][2] = z2;
    }
    __syncthreads();
    if (t == 0) {
        float q0 = 0.f, q1 = 0.f, q2 = 0.f;
        #pragma unroll
        for (int w = 0; w < 8; w++) {
            q0 += zred[w][0]; q1 += zred[w][1]; q2 += zred[w][2];
        }
        qv[0] = q0; qv[1] = q1; qv[2] = q2;
    }
    __syncthreads();

    // ----------------- back-end MLP -----------------
    if (t < 32) {
        float h = b4[t];
        h = fmaf(qv[0], W4[t * 3 + 0], h);
        h = fmaf(qv[1], W4[t * 3 + 1], h);
        h = fmaf(qv[2], W4[t * 3 + 2], h);
        h4s[t] = geluf(h);
    }
    __syncthreads();
    if (t < 64) {
        float acc = b5[t];
        #pragma unroll
        for (int h = 0; h < 32; h++) acc = fmaf(h4s[h], W5[t * 32 + h], acc);
        out[b * 64 + t] = acc;
    }
}

extern "C" void kernel_launch(void* const* d_in, const int* in_sizes, int n_in,
                              void* d_out, int out_size, void* d_ws, size_t ws_size,
                              hipStream_t stream) {
    (void)in_sizes; (void)n_in; (void)d_ws; (void)ws_size; (void)out_size;
    const float* x    = (const float*)d_in[0];
    const float* W1   = (const float*)d_in[1];
    const float* b1   = (const float*)d_in[2];
    const float* g_ln = (const float*)d_in[3];
    const float* b_ln = (const float*)d_in[4];
    const float* W2   = (const float*)d_in[5];
    const float* b2   = (const float*)d_in[6];
    const float* W3   = (const float*)d_in[7];
    const float* b3   = (const float*)d_in[8];
    const float* qw   = (const float*)d_in[9];
    const float* W4   = (const float*)d_in[10];
    const float* b4   = (const float*)d_in[11];
    const float* W5   = (const float*)d_in[12];
    const float* b5   = (const float*)d_in[13];
    float* out = (float*)d_out;

    qpu_kernel<<<BATCH, NT, 0, stream>>>(x, W1, b1, g_ln, b_ln, W2, b2,
                                         W3, b3, qw, W4, b4, W5, b5, out);
}

// Round 3
// 110.349 us; speedup vs baseline: 1.0283x; 1.0283x over previous
//
#include <hip/hip_runtime.h>
#include <math.h>

#define NQ   12
#define NL   6
#define DIM  4096
#define BATCH 256
#define NT   512
#define PI2  9.869604401089358f   // pi*pi

__device__ __forceinline__ float geluf(float x) {
    return 0.5f * x * (1.0f + erff(x * 0.70710678118654752f));
}

__device__ __forceinline__ float2 cmul(float2 a, float2 b) {
    return make_float2(fmaf(a.x, b.x, -a.y * b.y), fmaf(a.x, b.y, a.y * b.x));
}
__device__ __forceinline__ float2 cadd(float2 a, float2 b) {
    return make_float2(a.x + b.x, a.y + b.y);
}
__device__ __forceinline__ float2 cscale(float2 a, float s) {
    return make_float2(a.x * s, a.y * s);
}

// ring-CNOT gather map (verified on HW in R1)
__device__ __forceinline__ int gmap(int j) {
    return ((j ^ (j >> 1)) & 0x3FF)
         | ((((j >> 10) ^ (j >> 11) ^ j) & 1) << 10)
         | ((((j >> 11) ^ j) & 1) << 11);
}

// cross-lane xor-1 / xor-2 via DPP quad_perm (VALU pipe, not LDS pipe)
template<int CTRL>
__device__ __forceinline__ float2 dppx(float2 v) {
    int x = __builtin_amdgcn_update_dpp(0, __float_as_int(v.x), CTRL, 0xF, 0xF, true);
    int y = __builtin_amdgcn_update_dpp(0, __float_as_int(v.y), CTRL, 0xF, 0xF, true);
    return make_float2(__int_as_float(x), __int_as_float(y));
}

__device__ __forceinline__ float2 shflx(float2 v, int mask) {
    return make_float2(__shfl_xor(v.x, mask, 64), __shfl_xor(v.y, mask, 64));
}

// in-register butterfly on register-bit `bit`
__device__ __forceinline__ void reg_gate(float2* a, const float2* Ug, int bit) {
    const float2 u00 = Ug[0], u01 = Ug[1], u10 = Ug[2], u11 = Ug[3];
    #pragma unroll
    for (int m = 0; m < 8; m++) {
        if (m & bit) continue;
        float2 x0 = a[m], x1 = a[m | bit];
        a[m]       = cadd(cmul(u00, x0), cmul(u01, x1));
        a[m | bit] = cadd(cmul(u10, x0), cmul(u11, x1));
    }
}

__global__ __launch_bounds__(NT)
void qpu_kernel(const float* __restrict__ x,   const float* __restrict__ W1, const float* __restrict__ b1,
                const float* __restrict__ g_ln, const float* __restrict__ b_ln,
                const float* __restrict__ W2,  const float* __restrict__ b2,
                const float* __restrict__ W3,  const float* __restrict__ b3,
                const float* __restrict__ qw,  const float* __restrict__ W4, const float* __restrict__ b4,
                const float* __restrict__ W5,  const float* __restrict__ b5,
                float* __restrict__ out)
{
    // two padded state buffers (slot j -> j + (j>>4)); RT2/gather uses bufA,
    // RT1/transpose uses bufB. Each RT = write + 1 barrier + read.
    __shared__ float2 bufA[4352];
    __shared__ float2 bufB[4352];
    __shared__ float2 Um[NL * NQ * 4];
    __shared__ float  xs[256];
    __shared__ float  h1n[128];
    __shared__ float  h2s[64];
    __shared__ float  xqs[NQ];
    __shared__ float  musd[2];
    __shared__ float  qv[3];
    __shared__ float  h4s[32];
    __shared__ float  zred[8][3];

    const int t = threadIdx.x;
    const int b = blockIdx.x;

    // ----------------- front-end MLP -----------------
    if (t < 256) xs[t] = x[b * 256 + t];
    __syncthreads();

    if (t < 128) {
        const float4* w = (const float4*)(W1 + t * 256);
        float a0 = 0.f, a1 = 0.f, a2 = 0.f, a3 = 0.f;
        #pragma unroll 8
        for (int k = 0; k < 64; k++) {
            float4 wv = w[k];
            const float* xp = &xs[4 * k];
            a0 = fmaf(wv.x, xp[0], a0);
            a1 = fmaf(wv.y, xp[1], a1);
            a2 = fmaf(wv.z, xp[2], a2);
            a3 = fmaf(wv.w, xp[3], a3);
        }
        h1n[t] = geluf((a0 + a1) + (a2 + a3) + b1[t]);
    }
    __syncthreads();

    if (t < 64) {
        float v0 = h1n[t], v1 = h1n[t + 64];
        float s1 = v0 + v1;
        float s2 = fmaf(v0, v0, v1 * v1);
        #pragma unroll
        for (int off = 32; off > 0; off >>= 1) {
            s1 += __shfl_down(s1, off);
            s2 += __shfl_down(s2, off);
        }
        if (t == 0) {
            float mu  = s1 * (1.f / 128.f);
            float var = s2 * (1.f / 128.f) - mu * mu;
            musd[0] = mu;
            musd[1] = rsqrtf(var + 1e-5f);
        }
    }
    __syncthreads();
    if (t < 128) h1n[t] = (h1n[t] - musd[0]) * musd[1] * g_ln[t] + b_ln[t];
    __syncthreads();

    if (t < 64) {
        const float4* w = (const float4*)(W2 + t * 128);
        float a0 = 0.f, a1 = 0.f, a2 = 0.f, a3 = 0.f;
        #pragma unroll 8
        for (int k = 0; k < 32; k++) {
            float4 wv = w[k];
            const float* hp = &h1n[4 * k];
            a0 = fmaf(wv.x, hp[0], a0);
            a1 = fmaf(wv.y, hp[1], a1);
            a2 = fmaf(wv.z, hp[2], a2);
            a3 = fmaf(wv.w, hp[3], a3);
        }
        h2s[t] = geluf((a0 + a1) + (a2 + a3) + b2[t]);
    }
    __syncthreads();

    if (t < NQ) {
        const float4* w = (const float4*)(W3 + t * 64);
        float a0 = 0.f, a1 = 0.f, a2 = 0.f, a3 = 0.f;
        #pragma unroll
        for (int k = 0; k < 16; k++) {
            float4 wv = w[k];
            const float* hp = &h2s[4 * k];
            a0 = fmaf(wv.x, hp[0], a0);
            a1 = fmaf(wv.y, hp[1], a1);
            a2 = fmaf(wv.z, hp[2], a2);
            a3 = fmaf(wv.w, hp[3], a3);
        }
        xqs[t] = tanhf((a0 + a1) + (a2 + a3) + b3[t]);
    }
    __syncthreads();

    // ----------------- gate matrices (encoding RYs pre-merged) -----------------
    if (t < NL * NQ) {
        const int l = t / NQ;
        const int i = t % NQ;
        float a  = qw[t * 3 + 0];
        float bb = qw[t * 3 + 1];
        float c  = qw[t * 3 + 2];
        float sb, cb;   sincosf(0.5f * bb, &sb, &cb);
        float apc = 0.5f * (a + c), amc = 0.5f * (a - c);
        float sapc, capc; sincosf(apc, &sapc, &capc);
        float samc, camc; sincosf(amc, &samc, &camc);
        float2 u00 = make_float2( cb * capc, -cb * sapc);
        float2 u01 = make_float2(-sb * camc, -sb * samc);
        float2 u10 = make_float2( sb * camc, -sb * samc);
        float2 u11 = make_float2( cb * capc,  cb * sapc);

        float theta = 0.f;
        bool merge = false;
        if (l == 0)      { theta = xqs[i] * PI2;        merge = true; }
        else if (l & 1)  { theta = xqs[i] * PI2 * 0.5f; merge = true; }
        if (merge) {
            float sy, cy; sincosf(0.5f * theta, &sy, &cy);
            float2 m00 = cadd(cscale(u00,  cy), cscale(u01, sy));
            float2 m01 = cadd(cscale(u00, -sy), cscale(u01, cy));
            float2 m10 = cadd(cscale(u10,  cy), cscale(u11, sy));
            float2 m11 = cadd(cscale(u10, -sy), cscale(u11, cy));
            u00 = m00; u01 = m01; u10 = m10; u11 = m11;
        }
        Um[t * 4 + 0] = u00;
        Um[t * 4 + 1] = u01;
        Um[t * 4 + 2] = u10;
        Um[t * 4 + 3] = u11;
    }
    __syncthreads();

    // ----------------- layer 0: direct product state -----------------
    // state after layer-0 gates is a product state: amp(j) = prod_b col0(qubit 11-b)[j_b].
    // Build in arrangement B: reg m holds j = (m<<9) | t.
    float2 a[8];
    {
        const float2* U0 = Um;
        float2 P = ((t >> 0) & 1) ? U0[11 * 4 + 2] : U0[11 * 4 + 0];  // bit0 -> qubit 11
        #pragma unroll
        for (int bb = 1; bb < 9; bb++) {
            const float2* Uq = &U0[(11 - bb) * 4];
            float2 fac = ((t >> bb) & 1) ? Uq[2] : Uq[0];
            P = cmul(P, fac);
        }
        float2 b0 = cmul(P, U0[2 * 4 + 0]);   // bit9 (qubit 2) = 0
        float2 b1 = cmul(P, U0[2 * 4 + 2]);   // bit9 = 1
        float2 a00 = cmul(b0, U0[1 * 4 + 0]); // bit10 (qubit 1) = 0
        float2 a01 = cmul(b1, U0[1 * 4 + 0]);
        float2 a10 = cmul(b0, U0[1 * 4 + 2]); // bit10 = 1
        float2 a11 = cmul(b1, U0[1 * 4 + 2]);
        float2 f11 = U0[0 * 4 + 0], g11 = U0[0 * 4 + 2]; // bit11 (qubit 0)
        a[0] = cmul(a00, f11); a[1] = cmul(a01, f11);
        a[2] = cmul(a10, f11); a[3] = cmul(a11, f11);
        a[4] = cmul(a00, g11); a[5] = cmul(a01, g11);
        a[6] = cmul(a10, g11); a[7] = cmul(a11, g11);
    }

    // layer-0 boundary: ring-0 fold (RT2; no CZ after even layers)
    {
        float2* wa = &bufA[t + (t >> 4)];
        #pragma unroll
        for (int m = 0; m < 8; m++) wa[m * 544] = a[m];   // slot((m<<9)|t)
        __syncthreads();
        #pragma unroll
        for (int m = 0; m < 8; m++) {
            const int src = gmap(8 * t + m);
            a[m] = bufA[src + (src >> 4)];
        }
    }

    // ----------------- layers 1..5 -----------------
    // arrangement A at layer start: reg m holds j = 8t + m
    //   j bits 0-2 = m, bits 3-8 = lane bits 0-5, bits 9-11 = wave bits
    #pragma unroll 1
    for (int l = 1; l < NL; l++) {
        const float2* UL = &Um[l * NQ * 4];

        // gates on j bits 0,1,2 (qubits 11,10,9): in-register
        reg_gate(a, &UL[11 * 4], 1);
        reg_gate(a, &UL[10 * 4], 2);
        reg_gate(a, &UL[ 9 * 4], 4);

        // gates on j bits 3..8 (qubits 8..3): cross-lane
        #pragma unroll
        for (int k = 0; k < 6; k++) {
            const float2* Ug = &UL[(8 - k) * 4];
            const float2 u00 = Ug[0], u01 = Ug[1], u10 = Ug[2], u11 = Ug[3];
            const bool sel = (t >> k) & 1;
            const float2 cA = sel ? u11 : u00;
            const float2 cB = sel ? u10 : u01;
            #pragma unroll
            for (int m = 0; m < 8; m++) {
                float2 v;
                if      (k == 0) v = dppx<0xB1>(a[m]);   // quad_perm xor1
                else if (k == 1) v = dppx<0x4E>(a[m]);   // quad_perm xor2
                else             v = shflx(a[m], 1 << k);
                a[m] = cadd(cmul(cA, a[m]), cmul(cB, v));
            }
        }

        // RT1: transpose reg bits <-> wave bits (A -> B) through bufB
        {
            float2* wb = &bufB[8 * t + (t >> 1)];
            #pragma unroll
            for (int m = 0; m < 8; m++) wb[m] = a[m];     // slot(8t+m)
            __syncthreads();
            const float2* rb = &bufB[t + (t >> 4)];
            #pragma unroll
            for (int m = 0; m < 8; m++) a[m] = rb[m * 544]; // slot((m<<9)|t)
        }

        // gates on j bits 9,10,11 (qubits 2,1,0): now in-register
        reg_gate(a, &UL[2 * 4], 1);
        reg_gate(a, &UL[1 * 4], 2);
        reg_gate(a, &UL[0 * 4], 4);

        // RT2: ring-l fold (+CZ sign for l=1,3) back to arrangement A
        if (l < NL - 1) {
            float2* wa = &bufA[t + (t >> 4)];
            #pragma unroll
            for (int m = 0; m < 8; m++) wa[m * 544] = a[m];
            __syncthreads();
            const bool czl = (l == 1) || (l == 3);
            #pragma unroll
            for (int m = 0; m < 8; m++) {
                const int j = 8 * t + m;
                const int src = gmap(j);
                float2 v = bufA[src + (src >> 4)];
                if (czl && (__popc(j & (j << 2) & 0xAA8) & 1)) { v.x = -v.x; v.y = -v.y; }
                a[m] = v;
            }
        }
    }

    // ----------------- measurement -----------------
    // regs hold arrangement B: j = (m<<9) | t (pre-ring-5). Ring-5 folds into
    // parities (bit11<-0x7FF, bit10<-0xC00, bit9<-0xE00); CZ-5 has no effect on |amp|^2.
    float p[8];
    #pragma unroll
    for (int m = 0; m < 8; m++) p[m] = fmaf(a[m].x, a[m].x, a[m].y * a[m].y);

    float s03 = (p[0] - p[1] - p[2] + p[3]) + (p[4] - p[5] - p[6] + p[7]);
    float z0 = (__popc(t) & 1) ? -s03 : s03;
    float z1 = (p[0] + p[1]) - (p[2] + p[3]) - (p[4] + p[5]) + (p[6] + p[7]);
    float z2 = (p[0] - p[1] - p[2] + p[3]) - (p[4] - p[5] - p[6] + p[7]);

    #pragma unroll
    for (int off = 32; off > 0; off >>= 1) {
        z0 += __shfl_down(z0, off);
        z1 += __shfl_down(z1, off);
        z2 += __shfl_down(z2, off);
    }
    if ((t & 63) == 0) {
        zred[t >> 6][0] = z0;
        zred[t >> 6][1] = z1;
        zred[t >> 6][2] = z2;
    }
    __syncthreads();
    if (t == 0) {
        float q0 = 0.f, q1 = 0.f, q2 = 0.f;
        #pragma unroll
        for (int w = 0; w < 8; w++) {
            q0 += zred[w][0]; q1 += zred[w][1]; q2 += zred[w][2];
        }
        qv[0] = q0; qv[1] = q1; qv[2] = q2;
    }
    __syncthreads();

    // ----------------- back-end MLP -----------------
    if (t < 32) {
        float h = b4[t];
        h = fmaf(qv[0], W4[t * 3 + 0], h);
        h = fmaf(qv[1], W4[t * 3 + 1], h);
        h = fmaf(qv[2], W4[t * 3 + 2], h);
        h4s[t] = geluf(h);
    }
    __syncthreads();
    if (t < 64) {
        float acc = b5[t];
        #pragma unroll
        for (int h = 0; h < 32; h++) acc = fmaf(h4s[h], W5[t * 32 + h], acc);
        out[b * 64 + t] = acc;
    }
}

extern "C" void kernel_launch(void* const* d_in, const int* in_sizes, int n_in,
                              void* d_out, int out_size, void* d_ws, size_t ws_size,
                              hipStream_t stream) {
    (void)in_sizes; (void)n_in; (void)d_ws; (void)ws_size; (void)out_size;
    const float* x    = (const float*)d_in[0];
    const float* W1   = (const float*)d_in[1];
    const float* b1   = (const float*)d_in[2];
    const float* g_ln = (const float*)d_in[3];
    const float* b_ln = (const float*)d_in[4];
    const float* W2   = (const float*)d_in[5];
    const float* b2   = (const float*)d_in[6];
    const float* W3   = (const float*)d_in[7];
    const float* b3   = (const float*)d_in[8];
    const float* qw   = (const float*)d_in[9];
    const float* W4   = (const float*)d_in[10];
    const float* b4   = (const float*)d_in[11];
    const float* W5   = (const float*)d_in[12];
    const float* b5   = (const float*)d_in[13];
    float* out = (float*)d_out;

    qpu_kernel<<<BATCH, NT, 0, stream>>>(x, W1, b1, g_ln, b_ln, W2, b2,
                                         W3, b3, qw, W4, b4, W5, b5, out);
}

// Round 4
// 105.819 us; speedup vs baseline: 1.0723x; 1.0428x over previous
//
#include <hip/hip_runtime.h>
#include <math.h>

#define NQ   12
#define NL   6
#define BATCH 256
#define NT   1024      // 16 waves/CU = 4 waves/SIMD
#define PI2  9.869604401089358f   // pi*pi

__device__ __forceinline__ float geluf(float x) {
    return 0.5f * x * (1.0f + erff(x * 0.70710678118654752f));
}

// LDS pad: P(x) = x + (x>>4) + (x>>8). Strictly increasing -> injective.
// Verified conflict-free (<=2-way) for linear, sigma, and gmap patterns.
__device__ __forceinline__ int Pad(int x) { return x + (x >> 4) + (x >> 8); }

// sigma: swap j bits {2,3,4,5} <-> {8,9,10,11} (bits 0,1,6,7 fixed)
__device__ __forceinline__ int sigma(int x) {
    return (x & 0xC3) | ((x & 0x3C) << 6) | ((x >> 6) & 0x3C);
}

// ring-CNOT gather map (HW-verified R1/R2)
__device__ __forceinline__ int gmap(int j) {
    return ((j ^ (j >> 1)) & 0x3FF)
         | ((((j >> 10) ^ (j >> 11) ^ j) & 1) << 10)
         | ((((j >> 11) ^ j) & 1) << 11);
}

__device__ __forceinline__ float2 cmul(float2 a, float2 b) {
    return make_float2(fmaf(a.x, b.x, -a.y * b.y), fmaf(a.x, b.y, a.y * b.x));
}
__device__ __forceinline__ float2 cadd(float2 a, float2 b) {
    return make_float2(a.x + b.x, a.y + b.y);
}
__device__ __forceinline__ float2 cscale(float2 a, float s) {
    return make_float2(a.x * s, a.y * s);
}

// DPP cross-lane (VALU pipe): quad_perm xor1=0xB1, xor2=0x4E, row_ror:8 (=xor8 in 16-row)=0x128
template<int CTRL>
__device__ __forceinline__ float2 dppx(float2 v) {
    int x = __builtin_amdgcn_update_dpp(0, __float_as_int(v.x), CTRL, 0xF, 0xF, true);
    int y = __builtin_amdgcn_update_dpp(0, __float_as_int(v.y), CTRL, 0xF, 0xF, true);
    return make_float2(__int_as_float(x), __int_as_float(y));
}
// ds_swizzle BitMode (barrier-free LDS pipe): xor4=0x101F, xor16=0x401F
template<int OFF>
__device__ __forceinline__ float2 swzx(float2 v) {
    int x = __builtin_amdgcn_ds_swizzle(__float_as_int(v.x), OFF);
    int y = __builtin_amdgcn_ds_swizzle(__float_as_int(v.y), OFF);
    return make_float2(__int_as_float(x), __int_as_float(y));
}
__device__ __forceinline__ float2 shflx32(float2 v) {
    return make_float2(__shfl_xor(v.x, 32, 64), __shfl_xor(v.y, 32, 64));
}

__device__ __forceinline__ void gate_reg(float2* a, const float2* Ug, int bit) {
    const float2 u00 = Ug[0], u01 = Ug[1], u10 = Ug[2], u11 = Ug[3];
    #pragma unroll
    for (int m = 0; m < 4; m++) {
        if (m & bit) continue;
        float2 x0 = a[m], x1 = a[m | bit];
        a[m]       = cadd(cmul(u00, x0), cmul(u01, x1));
        a[m | bit] = cadd(cmul(u10, x0), cmul(u11, x1));
    }
}
template<int CTRL>
__device__ __forceinline__ void gate_dpp(float2* a, const float2* Ug, bool sel) {
    const float2 cA = sel ? Ug[3] : Ug[0];
    const float2 cB = sel ? Ug[2] : Ug[1];
    #pragma unroll
    for (int m = 0; m < 4; m++) {
        float2 v = dppx<CTRL>(a[m]);
        a[m] = cadd(cmul(cA, a[m]), cmul(cB, v));
    }
}
template<int OFF>
__device__ __forceinline__ void gate_swz(float2* a, const float2* Ug, bool sel) {
    const float2 cA = sel ? Ug[3] : Ug[0];
    const float2 cB = sel ? Ug[2] : Ug[1];
    #pragma unroll
    for (int m = 0; m < 4; m++) {
        float2 v = swzx<OFF>(a[m]);
        a[m] = cadd(cmul(cA, a[m]), cmul(cB, v));
    }
}
__device__ __forceinline__ void gate_shfl32(float2* a, const float2* Ug, bool sel) {
    const float2 cA = sel ? Ug[3] : Ug[0];
    const float2 cB = sel ? Ug[2] : Ug[1];
    #pragma unroll
    for (int m = 0; m < 4; m++) {
        float2 v = shflx32(a[m]);
        a[m] = cadd(cmul(cA, a[m]), cmul(cB, v));
    }
}

__global__ __launch_bounds__(NT)
void qpu_kernel(const float* __restrict__ x,   const float* __restrict__ W1, const float* __restrict__ b1,
                const float* __restrict__ g_ln, const float* __restrict__ b_ln,
                const float* __restrict__ W2,  const float* __restrict__ b2,
                const float* __restrict__ W3,  const float* __restrict__ b3,
                const float* __restrict__ qw,  const float* __restrict__ W4, const float* __restrict__ b4,
                const float* __restrict__ W5,  const float* __restrict__ b5,
                float* __restrict__ out)
{
    __shared__ float2 bufA[4368];       // Pad(4095)=4365
    __shared__ float2 bufB[4368];
    __shared__ float2 Um[NL * NQ * 4];
    __shared__ float  xs[256];
    __shared__ float  pr[128 * 9];      // split-K partials (stride 9: bank-clean)
    __shared__ float  h1n[128];
    __shared__ float  h2s[64];
    __shared__ float  xqs[NQ];
    __shared__ float  musd[2];
    __shared__ float  qv[3];
    __shared__ float  h4s[32];
    __shared__ float  zred[16][3];

    const int t = threadIdx.x;
    const int b = blockIdx.x;

    // ----------------- front-end MLP (split-K over all threads) -----------------
    if (t < 256) xs[t] = x[b * 256 + t];
    __syncthreads();

    // h1 = gelu(x @ W1.T + b1): 128 outs x 8 parts x 32 elems
    {
        const int o = t >> 3, part = t & 7;
        const float4* w = (const float4*)(W1 + o * 256) + part * 8;
        const float*  xp = xs + part * 32;
        float a0 = 0.f, a1 = 0.f, a2 = 0.f, a3 = 0.f;
        #pragma unroll
        for (int k = 0; k < 8; k++) {
            float4 wv = w[k];
            a0 = fmaf(wv.x, xp[4 * k + 0], a0);
            a1 = fmaf(wv.y, xp[4 * k + 1], a1);
            a2 = fmaf(wv.z, xp[4 * k + 2], a2);
            a3 = fmaf(wv.w, xp[4 * k + 3], a3);
        }
        pr[o * 9 + part] = (a0 + a1) + (a2 + a3);
    }
    __syncthreads();
    if (t < 128) {
        float s = 0.f;
        #pragma unroll
        for (int k = 0; k < 8; k++) s += pr[t * 9 + k];
        h1n[t] = geluf(s + b1[t]);
    }
    __syncthreads();

    // layernorm stats (wave 0)
    if (t < 64) {
        float v0 = h1n[t], v1 = h1n[t + 64];
        float s1 = v0 + v1;
        float s2 = fmaf(v0, v0, v1 * v1);
        #pragma unroll
        for (int off = 32; off > 0; off >>= 1) {
            s1 += __shfl_down(s1, off);
            s2 += __shfl_down(s2, off);
        }
        if (t == 0) {
            float mu  = s1 * (1.f / 128.f);
            float var = s2 * (1.f / 128.f) - mu * mu;
            musd[0] = mu;
            musd[1] = rsqrtf(var + 1e-5f);
        }
    }
    __syncthreads();
    if (t < 128) h1n[t] = (h1n[t] - musd[0]) * musd[1] * g_ln[t] + b_ln[t];
    __syncthreads();

    // h2: 64 outs x 8 parts x 16 elems
    if (t < 512) {
        const int o = t >> 3, part = t & 7;
        const float4* w = (const float4*)(W2 + o * 128) + part * 4;
        const float*  hp = h1n + part * 16;
        float a0 = 0.f, a1 = 0.f, a2 = 0.f, a3 = 0.f;
        #pragma unroll
        for (int k = 0; k < 4; k++) {
            float4 wv = w[k];
            a0 = fmaf(wv.x, hp[4 * k + 0], a0);
            a1 = fmaf(wv.y, hp[4 * k + 1], a1);
            a2 = fmaf(wv.z, hp[4 * k + 2], a2);
            a3 = fmaf(wv.w, hp[4 * k + 3], a3);
        }
        pr[o * 9 + part] = (a0 + a1) + (a2 + a3);
    }
    __syncthreads();
    if (t < 64) {
        float s = 0.f;
        #pragma unroll
        for (int k = 0; k < 8; k++) s += pr[t * 9 + k];
        h2s[t] = geluf(s + b2[t]);
    }
    __syncthreads();

    // xq: 12 outs x 8 parts x 8 elems
    if (t < 96) {
        const int o = t >> 3, part = t & 7;
        const float4* w = (const float4*)(W3 + o * 64) + part * 2;
        const float*  hp = h2s + part * 8;
        float4 w0 = w[0], w1 = w[1];
        float s = 0.f;
        s = fmaf(w0.x, hp[0], s); s = fmaf(w0.y, hp[1], s);
        s = fmaf(w0.z, hp[2], s); s = fmaf(w0.w, hp[3], s);
        s = fmaf(w1.x, hp[4], s); s = fmaf(w1.y, hp[5], s);
        s = fmaf(w1.z, hp[6], s); s = fmaf(w1.w, hp[7], s);
        pr[o * 9 + part] = s;
    }
    __syncthreads();
    if (t < NQ) {
        float s = 0.f;
        #pragma unroll
        for (int k = 0; k < 8; k++) s += pr[t * 9 + k];
        xqs[t] = tanhf(s + b3[t]);
    }
    __syncthreads();

    // ----------------- gate matrices (encoding RYs pre-merged) -----------------
    if (t < NL * NQ) {
        const int l = t / NQ;
        const int i = t % NQ;
        float a  = qw[t * 3 + 0];
        float bb = qw[t * 3 + 1];
        float c  = qw[t * 3 + 2];
        float sb, cb;   sincosf(0.5f * bb, &sb, &cb);
        float apc = 0.5f * (a + c), amc = 0.5f * (a - c);
        float sapc, capc; sincosf(apc, &sapc, &capc);
        float samc, camc; sincosf(amc, &samc, &camc);
        float2 u00 = make_float2( cb * capc, -cb * sapc);
        float2 u01 = make_float2(-sb * camc, -sb * samc);
        float2 u10 = make_float2( sb * camc, -sb * samc);
        float2 u11 = make_float2( cb * capc,  cb * sapc);

        float theta = 0.f;
        bool merge = false;
        if (l == 0)      { theta = xqs[i] * PI2;        merge = true; }
        else if (l & 1)  { theta = xqs[i] * PI2 * 0.5f; merge = true; }
        if (merge) {
            float sy, cy; sincosf(0.5f * theta, &sy, &cy);
            float2 m00 = cadd(cscale(u00,  cy), cscale(u01, sy));
            float2 m01 = cadd(cscale(u00, -sy), cscale(u01, cy));
            float2 m10 = cadd(cscale(u10,  cy), cscale(u11, sy));
            float2 m11 = cadd(cscale(u10, -sy), cscale(u11, cy));
            u00 = m00; u01 = m01; u10 = m10; u11 = m11;
        }
        Um[t * 4 + 0] = u00;
        Um[t * 4 + 1] = u01;
        Um[t * 4 + 2] = u10;
        Um[t * 4 + 3] = u11;
    }
    __syncthreads();

    // ----------------- layer 0: product state evaluated at gmap(j) -----------------
    // amp0(i) = prod_b U[11-b][i_b][0]; a[m] = amp0(gmap(4t+m)) = post-ring0 arrA state.
    float2 a[4];
    #pragma unroll
    for (int m = 0; m < 4; m++) {
        const int i = gmap(4 * t + m);
        float2 acc = (i & 1) ? Um[11 * 4 + 2] : Um[11 * 4 + 0];
        #pragma unroll
        for (int bb = 1; bb < 12; bb++) {
            const float2* Uq = &Um[(11 - bb) * 4];
            float2 f = ((i >> bb) & 1) ? Uq[2] : Uq[0];
            acc = cmul(acc, f);
        }
        a[m] = acc;
    }

    // ----------------- layers 1..5 -----------------
    // arrA: j = 4t+m. bits 0,1 = reg; 2..7 = lane; 8..11 = wave.
    // sigma-RT exposes bits 8..11 as lane-xor 1,2,4,8; ring-RT folds CNOT ring (+CZ).
    #pragma unroll 1
    for (int l = 1; l < NL; l++) {
        const float2* UL = &Um[l * NQ * 4];

        // arrA: qubits 11,10 (reg), 9..4 (lane xor 1,2,4,8,16,32)
        gate_reg(a, &UL[11 * 4], 1);
        gate_reg(a, &UL[10 * 4], 2);
        gate_dpp<0xB1>  (a, &UL[9 * 4], (t >> 0) & 1);
        gate_dpp<0x4E>  (a, &UL[8 * 4], (t >> 1) & 1);
        gate_swz<0x101F>(a, &UL[7 * 4], (t >> 2) & 1);
        gate_dpp<0x128> (a, &UL[6 * 4], (t >> 3) & 1);   // row_ror:8 == lane xor8
        gate_swz<0x401F>(a, &UL[5 * 4], (t >> 4) & 1);
        gate_shfl32     (a, &UL[4 * 4], (t >> 5) & 1);

        // RT1 (bufB): write linear, read sigma -> regs hold amp(sigma(4t+m))
        {
            const int base = Pad(4 * t);     // Pad(4t+m) = Pad(4t)+m (no carry)
            #pragma unroll
            for (int m = 0; m < 4; m++) bufB[base + m] = a[m];
            __syncthreads();
            const int sb = Pad(sigma(4 * t)); // sigma keeps bits 0,1 -> +m
            #pragma unroll
            for (int m = 0; m < 4; m++) a[m] = bufB[sb + m];
        }

        // arrB: qubits 3,2,1,0 at lane-xor 1,2,4,8
        gate_dpp<0xB1>  (a, &UL[3 * 4], (t >> 0) & 1);
        gate_dpp<0x4E>  (a, &UL[2 * 4], (t >> 1) & 1);
        gate_swz<0x101F>(a, &UL[1 * 4], (t >> 2) & 1);
        gate_dpp<0x128> (a, &UL[0 * 4], (t >> 3) & 1);

        // RT2 (bufA): write sigma (restores amp(i) at Pad(i)), read gmap (+CZ l=1,3)
        if (l < NL - 1) {
            const int sb = Pad(sigma(4 * t));
            #pragma unroll
            for (int m = 0; m < 4; m++) bufA[sb + m] = a[m];
            __syncthreads();
            const bool czl = (l == 1) || (l == 3);
            #pragma unroll
            for (int m = 0; m < 4; m++) {
                const int j = 4 * t + m;
                float2 v = bufA[Pad(gmap(j))];
                if (czl && (__popc(j & (j << 2) & 0xAA8) & 1)) { v.x = -v.x; v.y = -v.y; }
                a[m] = v;
            }
        }
    }

    // ----------------- measurement -----------------
    // Regs hold amp(sigma(4t+m)) pre-ring5. Ring-5 folds to parities of j:
    // f11 = par(j&0x7FF), f10 = par(j&0xC00), f9 = par(j&0xE00). CZ5 drops under |.|^2.
    float z0 = 0.f, z1 = 0.f, z2 = 0.f;
    #pragma unroll
    for (int m = 0; m < 4; m++) {
        const int j = sigma(4 * t + m);
        float p = fmaf(a[m].x, a[m].x, a[m].y * a[m].y);
        z0 += (__popc(j & 0x7FF) & 1) ? -p : p;
        z1 += (__popc(j & 0xC00) & 1) ? -p : p;
        z2 += (__popc(j & 0xE00) & 1) ? -p : p;
    }
    #pragma unroll
    for (int off = 32; off > 0; off >>= 1) {
        z0 += __shfl_down(z0, off);
        z1 += __shfl_down(z1, off);
        z2 += __shfl_down(z2, off);
    }
    if ((t & 63) == 0) {
        zred[t >> 6][0] = z0;
        zred[t >> 6][1] = z1;
        zred[t >> 6][2] = z2;
    }
    __syncthreads();
    if (t == 0) {
        float q0 = 0.f, q1 = 0.f, q2 = 0.f;
        #pragma unroll
        for (int w = 0; w < 16; w++) {
            q0 += zred[w][0]; q1 += zred[w][1]; q2 += zred[w][2];
        }
        qv[0] = q0; qv[1] = q1; qv[2] = q2;
    }
    __syncthreads();

    // ----------------- back-end MLP -----------------
    if (t < 32) {
        float h = b4[t];
        h = fmaf(qv[0], W4[t * 3 + 0], h);
        h = fmaf(qv[1], W4[t * 3 + 1], h);
        h = fmaf(qv[2], W4[t * 3 + 2], h);
        h4s[t] = geluf(h);
    }
    __syncthreads();
    if (t < 64) {
        float acc = b5[t];
        #pragma unroll
        for (int h = 0; h < 32; h++) acc = fmaf(h4s[h], W5[t * 32 + h], acc);
        out[b * 64 + t] = acc;
    }
}

extern "C" void kernel_launch(void* const* d_in, const int* in_sizes, int n_in,
                              void* d_out, int out_size, void* d_ws, size_t ws_size,
                              hipStream_t stream) {
    (void)in_sizes; (void)n_in; (void)d_ws; (void)ws_size; (void)out_size;
    const float* x    = (const float*)d_in[0];
    const float* W1   = (const float*)d_in[1];
    const float* b1   = (const float*)d_in[2];
    const float* g_ln = (const float*)d_in[3];
    const float* b_ln = (const float*)d_in[4];
    const float* W2   = (const float*)d_in[5];
    const float* b2   = (const float*)d_in[6];
    const float* W3   = (const float*)d_in[7];
    const float* b3   = (const float*)d_in[8];
    const float* qw   = (const float*)d_in[9];
    const float* W4   = (const float*)d_in[10];
    const float* b4   = (const float*)d_in[11];
    const float* W5   = (const float*)d_in[12];
    const float* b5   = (const float*)d_in[13];
    float* out = (float*)d_out;

    qpu_kernel<<<BATCH, NT, 0, stream>>>(x, W1, b1, g_ln, b_ln, W2, b2,
                                         W3, b3, qw, W4, b4, W5, b5, out);
}